// Round 2
// baseline (389.212 us; speedup 1.0000x reference)
//
#include <hip/hip_runtime.h>

// AttentionXL: CUR=1024, FULL=2048, BS=4, D=1024, HN=16, HD=64, PREV=1024
// f16 MFMA 16x16x32 everywhere; fp32 accumulate/softmax.
// Scores pre-scaled: qfu = (q+b+u)*0.125; qv = qfu + (v-u)*0.125 in-register.

typedef _Float16 half8 __attribute__((ext_vector_type(8)));
typedef _Float16 half4v __attribute__((ext_vector_type(4)));
typedef float f32x4 __attribute__((ext_vector_type(4)));

typedef const __attribute__((address_space(1))) void* gas_ptr;
typedef __attribute__((address_space(3))) void* las_ptr;

__device__ __forceinline__ void load_lds16(const void* g, void* l) {
  __builtin_amdgcn_global_load_lds((gas_ptr)g, (las_ptr)l, 16, 0, 0);
}

// ---------------------------------------------------------------------------
// prep: activation fp32->f16 with b-major row permute (blocks [0,14336)) +
// weight convert+transpose (blocks [14336,15616)).
//  in_q_h  [b*1024 + i][:] <- inputs[i*4+b][:]
//  in_full_h[b*2048 + j][:] <- full_inp[j*4+b][:]
//  in_pos_h plain copy.
// ---------------------------------------------------------------------------
__global__ __launch_bounds__(256) void prep(
    const float* __restrict__ inputs, const float* __restrict__ full_inp,
    const float* __restrict__ pos_emb, const float* __restrict__ Wq,
    const float* __restrict__ Wkv, const float* __restrict__ Wpos,
    const float* __restrict__ Wproj, _Float16* __restrict__ o_in,
    _Float16* __restrict__ o_full, _Float16* __restrict__ o_pos,
    _Float16* __restrict__ owq, _Float16* __restrict__ owkv,
    _Float16* __restrict__ owpos, _Float16* __restrict__ owproj) {
  __shared__ _Float16 tile[64][65];
  const int bx = blockIdx.x;
  const int t = threadIdx.x;
  if (bx < 14336) {
    size_t g = (size_t)bx * 256 + t;  // dst float4-group id
    const float* src;
    _Float16* dst;
    size_t sg;
    if (g < (1u << 20)) {  // inputs -> in_q_h, b-major
      const int rd = (int)(g >> 8), b = rd >> 10, i = rd & 1023;
      src = inputs; dst = o_in;
      sg = ((size_t)(i * 4 + b) << 8) + (g & 255);
    } else if (g < (3u << 20)) {  // full_inp -> in_full_h, b-major
      const size_t gd = g - (1u << 20);
      const int rd = (int)(gd >> 8), b = rd >> 11, j = rd & 2047;
      src = full_inp; dst = o_full;
      sg = ((size_t)(j * 4 + b) << 8) + (gd & 255);
      float4 vv = *(const float4*)(src + sg * 4);
      half4v hh;
      hh[0] = (_Float16)vv.x; hh[1] = (_Float16)vv.y;
      hh[2] = (_Float16)vv.z; hh[3] = (_Float16)vv.w;
      *(half4v*)(dst + gd * 4) = hh;
      return;
    } else {  // pos_emb plain
      const size_t gd = g - (3u << 20);
      float4 vv = *(const float4*)(pos_emb + gd * 4);
      half4v hh;
      hh[0] = (_Float16)vv.x; hh[1] = (_Float16)vv.y;
      hh[2] = (_Float16)vv.z; hh[3] = (_Float16)vv.w;
      *(half4v*)(o_pos + gd * 4) = hh;
      return;
    }
    // in_q_h path
    float4 vv = *(const float4*)(src + sg * 4);
    half4v hh;
    hh[0] = (_Float16)vv.x; hh[1] = (_Float16)vv.y;
    hh[2] = (_Float16)vv.z; hh[3] = (_Float16)vv.w;
    *(half4v*)(dst + (g & ((1u << 20) - 1)) * 4) = hh;
    return;
  }
  const int wb = bx - 14336;
  const float* W;
  _Float16* Wt;
  int N, tidx;
  if (wb < 256) { W = Wq; Wt = owq; N = 1024; tidx = wb; }
  else if (wb < 768) { W = Wkv; Wt = owkv; N = 2048; tidx = wb - 256; }
  else if (wb < 1024) { W = Wpos; Wt = owpos; N = 1024; tidx = wb - 768; }
  else { W = Wproj; Wt = owproj; N = 1024; tidx = wb - 1024; }
  const int K = 1024;
  const int n0 = (tidx % (N >> 6)) * 64, k0 = (tidx / (N >> 6)) * 64;
  const int rr = t >> 2, cc = (t & 3) * 16;
#pragma unroll
  for (int i = 0; i < 4; ++i) {
    float4 v = *(const float4*)&W[(size_t)(k0 + rr) * N + n0 + cc + i * 4];
    tile[rr][cc + i * 4 + 0] = (_Float16)v.x;
    tile[rr][cc + i * 4 + 1] = (_Float16)v.y;
    tile[rr][cc + i * 4 + 2] = (_Float16)v.z;
    tile[rr][cc + i * 4 + 3] = (_Float16)v.w;
  }
  __syncthreads();
  const int n = t >> 2, kc = (t & 3) * 16;
#pragma unroll
  for (int i = 0; i < 4; ++i) {
    half4v h;
    h[0] = tile[kc + i * 4 + 0][n];
    h[1] = tile[kc + i * 4 + 1][n];
    h[2] = tile[kc + i * 4 + 2][n];
    h[3] = tile[kc + i * 4 + 3][n];
    *(half4v*)&Wt[(size_t)(n0 + n) * K + k0 + kc + i * 4] = h;
  }
}

// ---------------------------------------------------------------------------
// Fused q/kv/r GEMM (A matrices are b-major). 1408 blocks.
//   [0,256):    q  -> qfu[bh][i][d] = (q+b+u)*0.125
//   [256,1280): kv -> kf[bh][j][d]; V-half via LDS transpose -> vfT[bh][d][j]
//   [1280,1408): r -> rf[h][m][d]
// ---------------------------------------------------------------------------
__global__ __launch_bounds__(256, 2) void gemm3(
    const _Float16* __restrict__ Aq, const _Float16* __restrict__ Akv,
    const _Float16* __restrict__ Ar, const _Float16* __restrict__ Btq,
    const _Float16* __restrict__ Btkv, const _Float16* __restrict__ Btr,
    const float* __restrict__ bq, const float* __restrict__ bkv,
    const float* __restrict__ br, const float* __restrict__ uu,
    _Float16* __restrict__ qfu, _Float16* __restrict__ kf,
    _Float16* __restrict__ vfT, _Float16* __restrict__ rf) {
  __shared__ _Float16 smem[128 * 66];  // K-loop: As=smem[0..4K), Bs=[4K..8K); epilogue: 128x66 tile
  _Float16* As = smem;
  _Float16* Bs = smem + 4096;
  const int gb = blockIdx.x;
  const _Float16* A;
  const _Float16* Bt;
  const float* bias;
  int mode, bm, bn;
  if (gb < 256) {
    mode = 1; A = Aq; Bt = Btq; bias = bq;
    bn = (gb & 7) * 128; bm = (gb >> 3) * 128;
  } else if (gb < 1280) {
    mode = 2; A = Akv; Bt = Btkv; bias = bkv;
    const int j = gb - 256;
    bn = (j & 15) * 128; bm = (j >> 4) * 128;
  } else {
    mode = 3; A = Ar; Bt = Btr; bias = br;
    const int j = gb - 1280;
    bn = (j & 7) * 128; bm = (j >> 3) * 128;
  }
  const int K = 1024;
  const int t = threadIdx.x, w = t >> 6, l = t & 63;
  const int l15 = l & 15, l4 = l >> 4;
  const int wm = (w >> 1) * 64, wn = (w & 1) * 64;

  f32x4 acc[4][4];
  const f32x4 z4 = {0.f, 0.f, 0.f, 0.f};
#pragma unroll
  for (int i = 0; i < 4; ++i)
#pragma unroll
    for (int j = 0; j < 4; ++j) acc[i][j] = z4;

  const char* Abase = (const char*)A + (size_t)bm * K * 2;
  const char* Bbase = (const char*)Bt + (size_t)bn * K * 2;

  for (int k0 = 0; k0 < K; k0 += 32) {
    __syncthreads();
#pragma unroll
    for (int iss = 0; iss < 2; ++iss) {
      const int off = w * 1024 + iss * 4096 + l * 16;
      const int row = off >> 6, kb = off & 63;
      load_lds16(Abase + (size_t)row * (K * 2) + k0 * 2 + kb,
                 (char*)As + off);
      load_lds16(Bbase + (size_t)row * (K * 2) + k0 * 2 + kb,
                 (char*)Bs + off);
    }
    __syncthreads();
    half8 af[4], bf[4];
#pragma unroll
    for (int mt = 0; mt < 4; ++mt)
      af[mt] = *(const half8*)&As[(wm + mt * 16 + l15) * 32 + l4 * 8];
#pragma unroll
    for (int nt = 0; nt < 4; ++nt)
      bf[nt] = *(const half8*)&Bs[(wn + nt * 16 + l15) * 32 + l4 * 8];
#pragma unroll
    for (int mt = 0; mt < 4; ++mt)
#pragma unroll
      for (int nt = 0; nt < 4; ++nt)
        acc[mt][nt] = __builtin_amdgcn_mfma_f32_16x16x32_f16(
            af[mt], bf[nt], acc[mt][nt], 0, 0, 0);
  }

  if (mode == 2 && bn >= 1024) {
    // ---- V half: LDS transpose -> coalesced vfT[bh][d][j] stores ----
    const int b = bm >> 11, j0m = bm & 2047;
    const int hbase = (bn - 1024) >> 6;  // even
#pragma unroll
    for (int ch = 0; ch < 2; ++ch) {
      __syncthreads();
      if (((wn >> 6) & 1) == ch) {
#pragma unroll
        for (int mt = 0; mt < 4; ++mt)
#pragma unroll
          for (int r = 0; r < 4; ++r) {
            const int rowl = wm + mt * 16 + l4 * 4 + r;
#pragma unroll
            for (int nt = 0; nt < 4; ++nt) {
              const int coll = nt * 16 + l15;
              smem[rowl * 66 + coll] =
                  (_Float16)(acc[mt][nt][r] + bias[bn + wn + coll]);
            }
          }
      }
      __syncthreads();
#pragma unroll
      for (int it = 0; it < 4; ++it) {
        const int c = t + 256 * it;
        const int d = c >> 4, ck = c & 15;
        half8 v8;
#pragma unroll
        for (int z = 0; z < 8; ++z) v8[z] = smem[(ck * 8 + z) * 66 + d];
        *(half8*)&vfT[(((size_t)(b * 16 + hbase + ch) * 64 + d) << 11) + j0m +
                      ck * 8] = v8;
      }
    }
    return;
  }

#pragma unroll
  for (int mt = 0; mt < 4; ++mt)
#pragma unroll
    for (int r = 0; r < 4; ++r) {
      const int rowl = wm + mt * 16 + l4 * 4 + r;
#pragma unroll
      for (int nt = 0; nt < 4; ++nt) {
        const int col = bn + wn + nt * 16 + l15;
        const float val = acc[mt][nt][r] + bias[col];
        if (mode == 1) {
          const int b = bm >> 10, i0m = bm & 1023;
          const int h = col >> 6, d = col & 63;
          qfu[(((size_t)(b * 16 + h) * 1024 + i0m + rowl) << 6) + d] =
              (_Float16)((val + uu[col]) * 0.125f);
        } else if (mode == 2) {
          const int b = bm >> 11, j0m = bm & 2047;
          const int h = col >> 6, d = col & 63;
          kf[(((size_t)(b * 16 + h) * 2048 + j0m + rowl) << 6) + d] =
              (_Float16)val;
        } else {
          const int h = col >> 6, d = col & 63;
          rf[(((size_t)h * 2048 + bm + rowl) << 6) + d] = (_Float16)val;
        }
      }
    }
}

// ---------------------------------------------------------------------------
// proj GEMM: out f32 [M][N] = A @ Bt^T + bias
// ---------------------------------------------------------------------------
__global__ __launch_bounds__(256, 2) void gemm_proj(
    const _Float16* __restrict__ A, const _Float16* __restrict__ Bt,
    const float* __restrict__ bias, float* __restrict__ out0, int M, int N,
    int K) {
  __shared__ _Float16 As[128 * 32];
  __shared__ _Float16 Bs[128 * 32];
  const int t = threadIdx.x, w = t >> 6, l = t & 63;
  const int l15 = l & 15, l4 = l >> 4;
  const int bm = blockIdx.y * 128, bn = blockIdx.x * 128;
  const int wm = (w >> 1) * 64, wn = (w & 1) * 64;

  f32x4 acc[4][4];
  const f32x4 z4 = {0.f, 0.f, 0.f, 0.f};
#pragma unroll
  for (int i = 0; i < 4; ++i)
#pragma unroll
    for (int j = 0; j < 4; ++j) acc[i][j] = z4;

  const char* Abase = (const char*)A + (size_t)bm * K * 2;
  const char* Bbase = (const char*)Bt + (size_t)bn * K * 2;

  for (int k0 = 0; k0 < K; k0 += 32) {
    __syncthreads();
#pragma unroll
    for (int iss = 0; iss < 2; ++iss) {
      const int off = w * 1024 + iss * 4096 + l * 16;
      const int row = off >> 6, kb = off & 63;
      load_lds16(Abase + (size_t)row * (K * 2) + k0 * 2 + kb,
                 (char*)As + off);
      load_lds16(Bbase + (size_t)row * (K * 2) + k0 * 2 + kb,
                 (char*)Bs + off);
    }
    __syncthreads();
    half8 af[4], bf[4];
#pragma unroll
    for (int mt = 0; mt < 4; ++mt)
      af[mt] = *(const half8*)&As[(wm + mt * 16 + l15) * 32 + l4 * 8];
#pragma unroll
    for (int nt = 0; nt < 4; ++nt)
      bf[nt] = *(const half8*)&Bs[(wn + nt * 16 + l15) * 32 + l4 * 8];
#pragma unroll
    for (int mt = 0; mt < 4; ++mt)
#pragma unroll
      for (int nt = 0; nt < 4; ++nt)
        acc[mt][nt] = __builtin_amdgcn_mfma_f32_16x16x32_f16(
            af[mt], bf[nt], acc[mt][nt], 0, 0, 0);
  }

#pragma unroll
  for (int mt = 0; mt < 4; ++mt)
#pragma unroll
    for (int r = 0; r < 4; ++r) {
      const int row = bm + wm + mt * 16 + l4 * 4 + r;
#pragma unroll
      for (int nt = 0; nt < 4; ++nt) {
        const int col = bn + wn + nt * 16 + l15;
        out0[(size_t)row * N + col] = acc[mt][nt][r] + bias[col];
      }
    }
}

// ---------------------------------------------------------------------------
// MFMA flash attention v6.
//  - K/V^T staged in LDS (shared by all 4 waves); r read DIRECTLY from
//    global/L2 (rf = 4 MB total, ~512 KB per XCD slice with the swizzle ->
//    L2-resident; LDS ring was pure overhead at 2 blocks/CU occupancy).
//  - LDS 24 KB (ks+vts+pA) -> up to 6 blocks/CU by LDS; VGPR-limited ~4-5.
//  - position loads issued BEFORE content MFMAs (rb[5][2]) so their L2
//    latency hides under the LDS-fed content phase (in-order issue).
//  - qv fragments built in-register from (v-u)*0.125 (no qfv array).
//  - mask fast-path: mask logic only when wave-uniform cw < 63.
//  - XCD swizzle: same-bh blocks share dispatch residue mod 8.
// ---------------------------------------------------------------------------
__global__ __launch_bounds__(256, 4) void attn_mfma(
    const _Float16* __restrict__ qfu,  // [bh][1024][64]  (q+b+u)*0.125
    const _Float16* __restrict__ kf,   // [bh][2048][64]
    const _Float16* __restrict__ vfT,  // [bh][64][2048]
    const _Float16* __restrict__ rf,   // [h][2048][64]
    const float* __restrict__ u,       // [16][64]
    const float* __restrict__ v,       // [16][64]
    _Float16* __restrict__ attn_out)   // [i*4+b][1024] f16
{
  __shared__ _Float16 ks[64 * 64];     // [j][d] swizzled
  __shared__ _Float16 vts[64 * 64];    // [d][j] swizzled
  __shared__ _Float16 pA[4][16 * 64];  // per-wave probs, A-layout, swizzled

  const int t = threadIdx.x, w = t >> 6, l = t & 63;
  const int l15 = l & 15, l4 = l >> 4;
  const int id = blockIdx.x;
  // XCD swizzle: bh = ((id>>3)&7)*8 + (id&7); qtile = id>>6 (LPT: reversed)
  const int bh = ((id >> 3) & 7) * 8 + (id & 7);
  const int bx = 15 - (id >> 6);
  const int i0 = bx * 64;
  const int h = bh & 15, b = bh >> 4;

  const char* kfb = (const char*)(kf + (((size_t)bh * 2048) << 6));
  const char* vg = (const char*)(vfT + (((size_t)bh) << 17));
  const char* rg = (const char*)(rf + (((size_t)h) << 17));

  // q fragments; qv = qa + (v-u)*0.125 in-register
  half8 qa0, qa1, qv0, qv1;
  {
    const size_t qo = (((size_t)bh * 1024 + i0 + w * 16 + l15) << 6) + l4 * 8;
    qa0 = *(const half8*)(qfu + qo);
    qa1 = *(const half8*)(qfu + qo + 32);
    half8 dl0, dl1;
#pragma unroll
    for (int z = 0; z < 8; ++z) {
      const int di = l4 * 8 + z;
      dl0[z] = (_Float16)(0.125f * (v[h * 64 + di] - u[h * 64 + di]));
      dl1[z] = (_Float16)(0.125f * (v[h * 64 + 32 + di] - u[h * 64 + 32 + di]));
    }
    qv0 = qa0 + dl0;
    qv1 = qa1 + dl1;
  }
  const f32x4 z4 = {0.f, 0.f, 0.f, 0.f};
  f32x4 o[4];
  o[0] = z4; o[1] = z4; o[2] = z4; o[3] = z4;
  float lsum[4] = {0.f, 0.f, 0.f, 0.f};

  const int njt = bx + 17;

  for (int jt = 0; jt < njt; ++jt) {
    const int j0 = jt * 64;
    const int m_base = j0 - i0 + 960;
    __syncthreads();  // prior tile's reads done before overwrite
    // ---- stage K, V^T (swizzled source) ----
    {
      const char* kg = kfb + (size_t)j0 * 128;
#pragma unroll
      for (int iss = 0; iss < 2; ++iss) {
        const int off = w * 1024 + iss * 4096 + l * 16;
        const int row = off >> 7;
        const int cph = (off >> 4) & 7;
        const int sw = ((cph ^ (row & 7)) << 4);
        load_lds16(kg + (size_t)row * 128 + sw, (char*)ks + off);
        load_lds16(vg + (size_t)row * 4096 + (size_t)j0 * 2 + sw,
                   (char*)vts + off);
      }
    }
    __syncthreads();

    // ---- issue position-row loads early (direct from global/L2) ----
    half8 rb[5][2];
#pragma unroll
    for (int p = 0; p < 5; ++p) {
      int m = m_base + (3 - w + p) * 16 + l15;
      m = m < 2047 ? m : 2047;  // clamp (same semantics as old ring staging)
      const half8* rrow = (const half8*)(rg + (size_t)m * 128);
      rb[p][0] = rrow[l4];
      rb[p][1] = rrow[4 + l4];
    }

    // ---- content scores (16x64 per wave), LDS-fed ----
    f32x4 sc[4];
#pragma unroll
    for (int nt = 0; nt < 4; ++nt) {
      const int row = nt * 16 + l15;
      const int rsw = row & 7;
      const half8 b0 = *(const half8*)&ks[row * 64 + ((l4 ^ rsw) * 8)];
      const half8 b1 = *(const half8*)&ks[row * 64 + (((4 + l4) ^ rsw) * 8)];
      f32x4 cc = z4;
      cc = __builtin_amdgcn_mfma_f32_16x16x32_f16(qa0, b0, cc, 0, 0, 0);
      cc = __builtin_amdgcn_mfma_f32_16x16x32_f16(qa1, b1, cc, 0, 0, 0);
      sc[nt] = cc;
    }
    // ---- position scores: 5 tiles over this wave's 79-wide window ----
    f32x4 accP[5];
#pragma unroll
    for (int p = 0; p < 5; ++p) {
      f32x4 cc = z4;
      cc = __builtin_amdgcn_mfma_f32_16x16x32_f16(qv0, rb[p][0], cc, 0, 0, 0);
      cc = __builtin_amdgcn_mfma_f32_16x16x32_f16(qv1, rb[p][1], cc, 0, 0, 0);
      accP[p] = cc;
    }

    // ---- softmax + P into A-layout (scores pre-scaled by 0.125) ----
    const int cw = i0 - j0 + 1024 + 16 * w;  // mask: jl > cw + (4*l4+r)
    if (cw >= 63) {  // wave-uniform: no masking possible in this tile
#pragma unroll
      for (int r = 0; r < 4; ++r) {
        const int thr = 4 * l4 + r;
        const int srcl = (l4 << 4) | ((15 + l15 - thr) & 15);
        float rot[5];
#pragma unroll
        for (int p = 0; p < 5; ++p) rot[p] = __shfl(accP[p][r], srcl, 64);
        float esum = 0.f;
        const int sw2 = (thr & 7) * 8;
#pragma unroll
        for (int nt = 0; nt < 4; ++nt) {
          const float pv = (l15 <= thr) ? rot[nt] : rot[nt + 1];
          const float e = __expf(sc[nt][r] + pv);
          esum += e;
          pA[w][thr * 64 + ((16 * nt + l15) ^ sw2)] = (_Float16)e;
        }
        lsum[r] += esum;
      }
    } else {
#pragma unroll
      for (int r = 0; r < 4; ++r) {
        const int thr = 4 * l4 + r;
        const int srcl = (l4 << 4) | ((15 + l15 - thr) & 15);
        float rot[5];
#pragma unroll
        for (int p = 0; p < 5; ++p) rot[p] = __shfl(accP[p][r], srcl, 64);
        float esum = 0.f;
        const int sw2 = (thr & 7) * 8;
#pragma unroll
        for (int nt = 0; nt < 4; ++nt) {
          const float pv = (l15 <= thr) ? rot[nt] : rot[nt + 1];
          const bool masked = (16 * nt + l15) > (cw + thr);
          const float e = masked ? 0.f : __expf(sc[nt][r] + pv);
          esum += e;
          pA[w][thr * 64 + ((16 * nt + l15) ^ sw2)] = (_Float16)e;
        }
        lsum[r] += esum;
      }
    }
    // ---- PV: O += P.V ----
#pragma unroll
    for (int kk = 0; kk < 2; ++kk) {
      const half8 a8 = *(const half8*)&pA[w][l15 * 64 + ((kk * 32 + l4 * 8) ^
                                                        ((l15 & 7) * 8))];
#pragma unroll
      for (int nt = 0; nt < 4; ++nt) {
        const int row = nt * 16 + l15;
        const half8 b8 =
            *(const half8*)&vts[row * 64 + ((((kk << 2) + l4) ^ (row & 7)) * 8)];
        o[nt] = __builtin_amdgcn_mfma_f32_16x16x32_f16(a8, b8, o[nt], 0, 0, 0);
      }
    }
  }

  // ---- epilogue ----
#pragma unroll
  for (int r = 0; r < 4; ++r) {
    float s = lsum[r];
    s += __shfl_xor(s, 1, 64);
    s += __shfl_xor(s, 2, 64);
    s += __shfl_xor(s, 4, 64);
    s += __shfl_xor(s, 8, 64);
    const float inv = 1.0f / s;
    const int i = i0 + w * 16 + l4 * 4 + r;
    const size_t base = ((size_t)i * 4 + b) * 1024 + h * 64;
#pragma unroll
    for (int nt = 0; nt < 4; ++nt)
      attn_out[base + nt * 16 + l15] = (_Float16)(o[nt][r] * inv);
  }
}

// ---------------------------------------------------------------------------
extern "C" void kernel_launch(void* const* d_in, const int* in_sizes, int n_in,
                              void* d_out, int out_size, void* d_ws,
                              size_t ws_size, hipStream_t stream) {
  const float* inputs   = (const float*)d_in[0];
  const float* pos_emb  = (const float*)d_in[1];
  const float* full_inp = (const float*)d_in[2];
  const float* u        = (const float*)d_in[3];
  const float* v        = (const float*)d_in[4];
  const float* W_kv   = (const float*)d_in[6];
  const float* b_kv   = (const float*)d_in[7];
  const float* W_q    = (const float*)d_in[8];
  const float* b_q    = (const float*)d_in[9];
  const float* W_pos  = (const float*)d_in[10];
  const float* b_pos  = (const float*)d_in[11];
  const float* W_proj = (const float*)d_in[12];
  const float* b_proj = (const float*)d_in[13];
  float* out = (float*)d_out;

  char* ws = (char*)d_ws;
  const size_t MB = 1024 * 1024;
  _Float16* in_q_h    = (_Float16*)(ws);            // 8 MB  (b-major 4096x1024)
  _Float16* in_full_h = (_Float16*)(ws + 8 * MB);   // 16 MB (b-major 8192x1024)
  _Float16* in_pos_h  = (_Float16*)(ws + 24 * MB);  // 4 MB  (2048x1024)
  _Float16* attn_h    = (_Float16*)(ws + 28 * MB);  // 8 MB  (4096x1024)
  _Float16* wq_t      = (_Float16*)(ws + 36 * MB);  // 2 MB
  _Float16* wkv_t     = (_Float16*)(ws + 38 * MB);  // 4 MB
  _Float16* wpos_t    = (_Float16*)(ws + 42 * MB);  // 2 MB
  _Float16* wproj_t   = (_Float16*)(ws + 44 * MB);  // 2 MB
  _Float16* qfu       = (_Float16*)(ws + 46 * MB);  // 8 MB  [bh][1024][64]
  _Float16* kf        = (_Float16*)(ws + 54 * MB);  // 16 MB [bh][2048][64]
  _Float16* vfT       = (_Float16*)(ws + 70 * MB);  // 16 MB [bh][64][2048]
  _Float16* rf        = (_Float16*)(ws + 86 * MB);  // 4 MB  [h][2048][64]

  const dim3 blk(256);
  prep<<<dim3(15616), blk, 0, stream>>>(inputs, full_inp, pos_emb, W_q, W_kv,
                                        W_pos, W_proj, in_q_h, in_full_h,
                                        in_pos_h, wq_t, wkv_t, wpos_t, wproj_t);
  gemm3<<<dim3(1408), blk, 0, stream>>>(in_q_h, in_full_h, in_pos_h, wq_t,
                                        wkv_t, wpos_t, b_q, b_kv, b_pos, u,
                                        qfu, kf, vfT, rf);
  attn_mfma<<<dim3(1024), blk, 0, stream>>>(qfu, kf, vfT, rf, u, v, attn_h);
  gemm_proj<<<dim3(8, 32), blk, 0, stream>>>(attn_h, wproj_t, b_proj, out,
                                             4096, 1024, 1024);
}

// Round 3
// 340.353 us; speedup vs baseline: 1.1436x; 1.1436x over previous
//
#include <hip/hip_runtime.h>

// AttentionXL: CUR=1024, FULL=2048, BS=4, D=1024, HN=16, HD=64, PREV=1024
// f16 MFMA 16x16x32 everywhere; fp32 accumulate/softmax.
// Scores pre-scaled: qfu = (q+b+u)*0.125; qv = qfu + (v-u)*0.125 in-register.

typedef _Float16 half8 __attribute__((ext_vector_type(8)));
typedef _Float16 half4v __attribute__((ext_vector_type(4)));
typedef float f32x4 __attribute__((ext_vector_type(4)));

typedef const __attribute__((address_space(1))) void* gas_ptr;
typedef __attribute__((address_space(3))) void* las_ptr;

__device__ __forceinline__ void load_lds16(const void* g, void* l) {
  __builtin_amdgcn_global_load_lds((gas_ptr)g, (las_ptr)l, 16, 0, 0);
}

// ---------------------------------------------------------------------------
// prep: activation fp32->f16 with b-major row permute (blocks [0,14336)) +
// weight convert+transpose (blocks [14336,15616)).
//  in_q_h  [b*1024 + i][:] <- inputs[i*4+b][:]
//  in_full_h[b*2048 + j][:] <- full_inp[j*4+b][:]
//  in_pos_h plain copy.
// ---------------------------------------------------------------------------
__global__ __launch_bounds__(256) void prep(
    const float* __restrict__ inputs, const float* __restrict__ full_inp,
    const float* __restrict__ pos_emb, const float* __restrict__ Wq,
    const float* __restrict__ Wkv, const float* __restrict__ Wpos,
    const float* __restrict__ Wproj, _Float16* __restrict__ o_in,
    _Float16* __restrict__ o_full, _Float16* __restrict__ o_pos,
    _Float16* __restrict__ owq, _Float16* __restrict__ owkv,
    _Float16* __restrict__ owpos, _Float16* __restrict__ owproj) {
  __shared__ _Float16 tile[64][65];
  const int bx = blockIdx.x;
  const int t = threadIdx.x;
  if (bx < 14336) {
    size_t g = (size_t)bx * 256 + t;  // dst float4-group id
    const float* src;
    _Float16* dst;
    size_t sg;
    if (g < (1u << 20)) {  // inputs -> in_q_h, b-major
      const int rd = (int)(g >> 8), b = rd >> 10, i = rd & 1023;
      src = inputs; dst = o_in;
      sg = ((size_t)(i * 4 + b) << 8) + (g & 255);
    } else if (g < (3u << 20)) {  // full_inp -> in_full_h, b-major
      const size_t gd = g - (1u << 20);
      const int rd = (int)(gd >> 8), b = rd >> 11, j = rd & 2047;
      src = full_inp; dst = o_full;
      sg = ((size_t)(j * 4 + b) << 8) + (gd & 255);
      float4 vv = *(const float4*)(src + sg * 4);
      half4v hh;
      hh[0] = (_Float16)vv.x; hh[1] = (_Float16)vv.y;
      hh[2] = (_Float16)vv.z; hh[3] = (_Float16)vv.w;
      *(half4v*)(dst + gd * 4) = hh;
      return;
    } else {  // pos_emb plain
      const size_t gd = g - (3u << 20);
      float4 vv = *(const float4*)(pos_emb + gd * 4);
      half4v hh;
      hh[0] = (_Float16)vv.x; hh[1] = (_Float16)vv.y;
      hh[2] = (_Float16)vv.z; hh[3] = (_Float16)vv.w;
      *(half4v*)(o_pos + gd * 4) = hh;
      return;
    }
    // in_q_h path
    float4 vv = *(const float4*)(src + sg * 4);
    half4v hh;
    hh[0] = (_Float16)vv.x; hh[1] = (_Float16)vv.y;
    hh[2] = (_Float16)vv.z; hh[3] = (_Float16)vv.w;
    *(half4v*)(dst + (g & ((1u << 20) - 1)) * 4) = hh;
    return;
  }
  const int wb = bx - 14336;
  const float* W;
  _Float16* Wt;
  int N, tidx;
  if (wb < 256) { W = Wq; Wt = owq; N = 1024; tidx = wb; }
  else if (wb < 768) { W = Wkv; Wt = owkv; N = 2048; tidx = wb - 256; }
  else if (wb < 1024) { W = Wpos; Wt = owpos; N = 1024; tidx = wb - 768; }
  else { W = Wproj; Wt = owproj; N = 1024; tidx = wb - 1024; }
  const int K = 1024;
  const int n0 = (tidx % (N >> 6)) * 64, k0 = (tidx / (N >> 6)) * 64;
  const int rr = t >> 2, cc = (t & 3) * 16;
#pragma unroll
  for (int i = 0; i < 4; ++i) {
    float4 v = *(const float4*)&W[(size_t)(k0 + rr) * N + n0 + cc + i * 4];
    tile[rr][cc + i * 4 + 0] = (_Float16)v.x;
    tile[rr][cc + i * 4 + 1] = (_Float16)v.y;
    tile[rr][cc + i * 4 + 2] = (_Float16)v.z;
    tile[rr][cc + i * 4 + 3] = (_Float16)v.w;
  }
  __syncthreads();
  const int n = t >> 2, kc = (t & 3) * 16;
#pragma unroll
  for (int i = 0; i < 4; ++i) {
    half4v h;
    h[0] = tile[kc + i * 4 + 0][n];
    h[1] = tile[kc + i * 4 + 1][n];
    h[2] = tile[kc + i * 4 + 2][n];
    h[3] = tile[kc + i * 4 + 3][n];
    *(half4v*)&Wt[(size_t)(n0 + n) * K + k0 + kc + i * 4] = h;
  }
}

// ---------------------------------------------------------------------------
// Fused q/kv/r GEMM (A matrices are b-major). 1408 blocks.
//   [0,256):    q  -> qfu[bh][i][d] = (q+b+u)*0.125
//   [256,1280): kv -> kf[bh][j][d]; V-half via LDS transpose -> vfT[bh][d][j]
//   [1280,1408): r -> rf[h][m][d]
// ---------------------------------------------------------------------------
__global__ __launch_bounds__(256, 2) void gemm3(
    const _Float16* __restrict__ Aq, const _Float16* __restrict__ Akv,
    const _Float16* __restrict__ Ar, const _Float16* __restrict__ Btq,
    const _Float16* __restrict__ Btkv, const _Float16* __restrict__ Btr,
    const float* __restrict__ bq, const float* __restrict__ bkv,
    const float* __restrict__ br, const float* __restrict__ uu,
    _Float16* __restrict__ qfu, _Float16* __restrict__ kf,
    _Float16* __restrict__ vfT, _Float16* __restrict__ rf) {
  __shared__ _Float16 smem[128 * 66];  // K-loop: As=smem[0..4K), Bs=[4K..8K); epilogue: 128x66 tile
  _Float16* As = smem;
  _Float16* Bs = smem + 4096;
  const int gb = blockIdx.x;
  const _Float16* A;
  const _Float16* Bt;
  const float* bias;
  int mode, bm, bn;
  if (gb < 256) {
    mode = 1; A = Aq; Bt = Btq; bias = bq;
    bn = (gb & 7) * 128; bm = (gb >> 3) * 128;
  } else if (gb < 1280) {
    mode = 2; A = Akv; Bt = Btkv; bias = bkv;
    const int j = gb - 256;
    bn = (j & 15) * 128; bm = (j >> 4) * 128;
  } else {
    mode = 3; A = Ar; Bt = Btr; bias = br;
    const int j = gb - 1280;
    bn = (j & 7) * 128; bm = (j >> 3) * 128;
  }
  const int K = 1024;
  const int t = threadIdx.x, w = t >> 6, l = t & 63;
  const int l15 = l & 15, l4 = l >> 4;
  const int wm = (w >> 1) * 64, wn = (w & 1) * 64;

  f32x4 acc[4][4];
  const f32x4 z4 = {0.f, 0.f, 0.f, 0.f};
#pragma unroll
  for (int i = 0; i < 4; ++i)
#pragma unroll
    for (int j = 0; j < 4; ++j) acc[i][j] = z4;

  const char* Abase = (const char*)A + (size_t)bm * K * 2;
  const char* Bbase = (const char*)Bt + (size_t)bn * K * 2;

  for (int k0 = 0; k0 < K; k0 += 32) {
    __syncthreads();
#pragma unroll
    for (int iss = 0; iss < 2; ++iss) {
      const int off = w * 1024 + iss * 4096 + l * 16;
      const int row = off >> 6, kb = off & 63;
      load_lds16(Abase + (size_t)row * (K * 2) + k0 * 2 + kb,
                 (char*)As + off);
      load_lds16(Bbase + (size_t)row * (K * 2) + k0 * 2 + kb,
                 (char*)Bs + off);
    }
    __syncthreads();
    half8 af[4], bf[4];
#pragma unroll
    for (int mt = 0; mt < 4; ++mt)
      af[mt] = *(const half8*)&As[(wm + mt * 16 + l15) * 32 + l4 * 8];
#pragma unroll
    for (int nt = 0; nt < 4; ++nt)
      bf[nt] = *(const half8*)&Bs[(wn + nt * 16 + l15) * 32 + l4 * 8];
#pragma unroll
    for (int mt = 0; mt < 4; ++mt)
#pragma unroll
      for (int nt = 0; nt < 4; ++nt)
        acc[mt][nt] = __builtin_amdgcn_mfma_f32_16x16x32_f16(
            af[mt], bf[nt], acc[mt][nt], 0, 0, 0);
  }

  if (mode == 2 && bn >= 1024) {
    // ---- V half: LDS transpose -> coalesced vfT[bh][d][j] stores ----
    const int b = bm >> 11, j0m = bm & 2047;
    const int hbase = (bn - 1024) >> 6;  // even
#pragma unroll
    for (int ch = 0; ch < 2; ++ch) {
      __syncthreads();
      if (((wn >> 6) & 1) == ch) {
#pragma unroll
        for (int mt = 0; mt < 4; ++mt)
#pragma unroll
          for (int r = 0; r < 4; ++r) {
            const int rowl = wm + mt * 16 + l4 * 4 + r;
#pragma unroll
            for (int nt = 0; nt < 4; ++nt) {
              const int coll = nt * 16 + l15;
              smem[rowl * 66 + coll] =
                  (_Float16)(acc[mt][nt][r] + bias[bn + wn + coll]);
            }
          }
      }
      __syncthreads();
#pragma unroll
      for (int it = 0; it < 4; ++it) {
        const int c = t + 256 * it;
        const int d = c >> 4, ck = c & 15;
        half8 v8;
#pragma unroll
        for (int z = 0; z < 8; ++z) v8[z] = smem[(ck * 8 + z) * 66 + d];
        *(half8*)&vfT[(((size_t)(b * 16 + hbase + ch) * 64 + d) << 11) + j0m +
                      ck * 8] = v8;
      }
    }
    return;
  }

#pragma unroll
  for (int mt = 0; mt < 4; ++mt)
#pragma unroll
    for (int r = 0; r < 4; ++r) {
      const int rowl = wm + mt * 16 + l4 * 4 + r;
#pragma unroll
      for (int nt = 0; nt < 4; ++nt) {
        const int col = bn + wn + nt * 16 + l15;
        const float val = acc[mt][nt][r] + bias[col];
        if (mode == 1) {
          const int b = bm >> 10, i0m = bm & 1023;
          const int h = col >> 6, d = col & 63;
          qfu[(((size_t)(b * 16 + h) * 1024 + i0m + rowl) << 6) + d] =
              (_Float16)((val + uu[col]) * 0.125f);
        } else if (mode == 2) {
          const int b = bm >> 11, j0m = bm & 2047;
          const int h = col >> 6, d = col & 63;
          kf[(((size_t)(b * 16 + h) * 2048 + j0m + rowl) << 6) + d] =
              (_Float16)val;
        } else {
          const int h = col >> 6, d = col & 63;
          rf[(((size_t)h * 2048 + bm + rowl) << 6) + d] = (_Float16)val;
        }
      }
    }
}

// ---------------------------------------------------------------------------
// proj GEMM: out f32 [M][N] = A @ Bt^T + bias
// ---------------------------------------------------------------------------
__global__ __launch_bounds__(256, 2) void gemm_proj(
    const _Float16* __restrict__ A, const _Float16* __restrict__ Bt,
    const float* __restrict__ bias, float* __restrict__ out0, int M, int N,
    int K) {
  __shared__ _Float16 As[128 * 32];
  __shared__ _Float16 Bs[128 * 32];
  const int t = threadIdx.x, w = t >> 6, l = t & 63;
  const int l15 = l & 15, l4 = l >> 4;
  const int bm = blockIdx.y * 128, bn = blockIdx.x * 128;
  const int wm = (w >> 1) * 64, wn = (w & 1) * 64;

  f32x4 acc[4][4];
  const f32x4 z4 = {0.f, 0.f, 0.f, 0.f};
#pragma unroll
  for (int i = 0; i < 4; ++i)
#pragma unroll
    for (int j = 0; j < 4; ++j) acc[i][j] = z4;

  const char* Abase = (const char*)A + (size_t)bm * K * 2;
  const char* Bbase = (const char*)Bt + (size_t)bn * K * 2;

  for (int k0 = 0; k0 < K; k0 += 32) {
    __syncthreads();
#pragma unroll
    for (int iss = 0; iss < 2; ++iss) {
      const int off = w * 1024 + iss * 4096 + l * 16;
      const int row = off >> 6, kb = off & 63;
      load_lds16(Abase + (size_t)row * (K * 2) + k0 * 2 + kb,
                 (char*)As + off);
      load_lds16(Bbase + (size_t)row * (K * 2) + k0 * 2 + kb,
                 (char*)Bs + off);
    }
    __syncthreads();
    half8 af[4], bf[4];
#pragma unroll
    for (int mt = 0; mt < 4; ++mt)
      af[mt] = *(const half8*)&As[(wm + mt * 16 + l15) * 32 + l4 * 8];
#pragma unroll
    for (int nt = 0; nt < 4; ++nt)
      bf[nt] = *(const half8*)&Bs[(wn + nt * 16 + l15) * 32 + l4 * 8];
#pragma unroll
    for (int mt = 0; mt < 4; ++mt)
#pragma unroll
      for (int nt = 0; nt < 4; ++nt)
        acc[mt][nt] = __builtin_amdgcn_mfma_f32_16x16x32_f16(
            af[mt], bf[nt], acc[mt][nt], 0, 0, 0);
  }

#pragma unroll
  for (int mt = 0; mt < 4; ++mt)
#pragma unroll
    for (int r = 0; r < 4; ++r) {
      const int row = bm + wm + mt * 16 + l4 * 4 + r;
#pragma unroll
      for (int nt = 0; nt < 4; ++nt) {
        const int col = bn + wn + nt * 16 + l15;
        out0[(size_t)row * N + col] = acc[mt][nt][r] + bias[col];
      }
    }
}

// ---------------------------------------------------------------------------
// MFMA flash attention v7.
//  - round-0 structure (verified 105.8 us) with the r-ring halved: the live
//    window is exactly 128 rows ([m_base, m_base+128) per tile; the stage of
//    [m_base+64,+128) is barrier-protected against the previous window's
//    reads), so a 128-slot ring suffices. slot&7 == m&7, swizzle unchanged.
//  - LDS 56 KB -> 40 KB (ks 8 + vts 8 + rs 16 + pA 8) -> 4 blocks/CU.
//  - launch_bounds(256,2): compiler allocates freely (~88 VGPR, no spills);
//    88 <= 128 -> 4 waves/SIMD, consistent with 4 blocks/CU.
//  - qv fragments built in-register from (v-u)*0.125 (no qfv array).
//  - mask fast-path: mask logic only when wave-uniform cw < 63.
//  - XCD swizzle: same-bh blocks share dispatch residue mod 8.
// ---------------------------------------------------------------------------
__global__ __launch_bounds__(256, 2) void attn_mfma(
    const _Float16* __restrict__ qfu,  // [bh][1024][64]  (q+b+u)*0.125
    const _Float16* __restrict__ kf,   // [bh][2048][64]
    const _Float16* __restrict__ vfT,  // [bh][64][2048]
    const _Float16* __restrict__ rf,   // [h][2048][64]
    const float* __restrict__ u,       // [16][64]
    const float* __restrict__ v,       // [16][64]
    _Float16* __restrict__ attn_out)   // [i*4+b][1024] f16
{
  __shared__ _Float16 ks[64 * 64];     // [j][d] swizzled
  __shared__ _Float16 vts[64 * 64];    // [d][j] swizzled
  __shared__ _Float16 rs[128 * 64];    // ring (slot = m & 127), swizzled
  __shared__ _Float16 pA[4][16 * 64];  // per-wave probs, A-layout, swizzled

  const int t = threadIdx.x, w = t >> 6, l = t & 63;
  const int l15 = l & 15, l4 = l >> 4;
  const int id = blockIdx.x;
  // XCD swizzle: bh = ((id>>3)&7)*8 + (id&7); qtile = id>>6 (LPT: reversed)
  const int bh = ((id >> 3) & 7) * 8 + (id & 7);
  const int bx = 15 - (id >> 6);
  const int i0 = bx * 64;
  const int h = bh & 15, b = bh >> 4;

  const char* kfb = (const char*)(kf + (((size_t)bh * 2048) << 6));
  const char* vg = (const char*)(vfT + (((size_t)bh) << 17));
  const char* rg = (const char*)(rf + (((size_t)h) << 17));

  // q fragments; qv = qa + (v-u)*0.125 in-register
  half8 qa0, qa1, qv0, qv1;
  {
    const size_t qo = (((size_t)bh * 1024 + i0 + w * 16 + l15) << 6) + l4 * 8;
    qa0 = *(const half8*)(qfu + qo);
    qa1 = *(const half8*)(qfu + qo + 32);
    half8 dl0, dl1;
#pragma unroll
    for (int z = 0; z < 8; ++z) {
      const int di = l4 * 8 + z;
      dl0[z] = (_Float16)(0.125f * (v[h * 64 + di] - u[h * 64 + di]));
      dl1[z] = (_Float16)(0.125f * (v[h * 64 + 32 + di] - u[h * 64 + 32 + di]));
    }
    qv0 = qa0 + dl0;
    qv1 = qa1 + dl1;
  }
  const f32x4 z4 = {0.f, 0.f, 0.f, 0.f};
  f32x4 o[4];
  o[0] = z4; o[1] = z4; o[2] = z4; o[3] = z4;
  float lsum[4] = {0.f, 0.f, 0.f, 0.f};

  const int mb0 = 960 - i0;  // m_base at jt=0 (>=0, multiple of 64)
  const int njt = bx + 17;

  // ---- prologue: stage initial 128-row r window into ring ----
#pragma unroll
  for (int iss = 0; iss < 4; ++iss) {
    const int off = w * 1024 + iss * 4096 + l * 16;
    const int q = off >> 7;  // 0..127
    const int cph = (off >> 4) & 7;
    const int slot = (mb0 + q) & 127;
    int m = mb0 + q;
    m = m < 2047 ? m : 2047;
    load_lds16(rg + (size_t)m * 128 + ((cph ^ (slot & 7)) << 4),
               (char*)rs + slot * 128 + cph * 16);
  }

  for (int jt = 0; jt < njt; ++jt) {
    const int j0 = jt * 64;
    const int m_base = j0 - i0 + 960;
    __syncthreads();  // prior tile's reads done before overwrite
    // ---- stage K, V^T (swizzled source) ----
    {
      const char* kg = kfb + (size_t)j0 * 128;
#pragma unroll
      for (int iss = 0; iss < 2; ++iss) {
        const int off = w * 1024 + iss * 4096 + l * 16;
        const int row = off >> 7;
        const int cph = (off >> 4) & 7;
        const int sw = ((cph ^ (row & 7)) << 4);
        load_lds16(kg + (size_t)row * 128 + sw, (char*)ks + off);
        load_lds16(vg + (size_t)row * 4096 + (size_t)j0 * 2 + sw,
                   (char*)vts + off);
      }
    }
    // ---- stage 64 new r rows [m_base+64, m_base+128) into ring ----
    if (jt > 0) {
      const int m0 = m_base + 64;
#pragma unroll
      for (int iss = 0; iss < 2; ++iss) {
        const int off = w * 1024 + iss * 4096 + l * 16;
        const int q = off >> 7;  // 0..63
        const int cph = (off >> 4) & 7;
        const int slot = (m0 + q) & 127;
        int m = m0 + q;
        m = m < 2047 ? m : 2047;
        load_lds16(rg + (size_t)m * 128 + ((cph ^ (slot & 7)) << 4),
                   (char*)rs + slot * 128 + cph * 16);
      }
    }
    __syncthreads();

    // ---- content scores (16x64 per wave) ----
    f32x4 sc[4];
#pragma unroll
    for (int nt = 0; nt < 4; ++nt) {
      const int row = nt * 16 + l15;
      const int rsw = row & 7;
      const half8 b0 = *(const half8*)&ks[row * 64 + ((l4 ^ rsw) * 8)];
      const half8 b1 = *(const half8*)&ks[row * 64 + (((4 + l4) ^ rsw) * 8)];
      f32x4 cc = z4;
      cc = __builtin_amdgcn_mfma_f32_16x16x32_f16(qa0, b0, cc, 0, 0, 0);
      cc = __builtin_amdgcn_mfma_f32_16x16x32_f16(qa1, b1, cc, 0, 0, 0);
      sc[nt] = cc;
    }
    // ---- position scores: 5 tiles over this wave's 79-wide window ----
    f32x4 accP[5];
#pragma unroll
    for (int p = 0; p < 5; ++p) {
      const int m = m_base + (3 - w + p) * 16 + l15;
      const int slot = m & 127;
      const int ssw = slot & 7;
      const half8 b0 = *(const half8*)&rs[slot * 64 + ((l4 ^ ssw) * 8)];
      const half8 b1 = *(const half8*)&rs[slot * 64 + (((4 + l4) ^ ssw) * 8)];
      f32x4 cc = z4;
      cc = __builtin_amdgcn_mfma_f32_16x16x32_f16(qv0, b0, cc, 0, 0, 0);
      cc = __builtin_amdgcn_mfma_f32_16x16x32_f16(qv1, b1, cc, 0, 0, 0);
      accP[p] = cc;
    }

    // ---- softmax + P into A-layout (scores pre-scaled by 0.125) ----
    const int cw = i0 - j0 + 1024 + 16 * w;  // mask: jl > cw + (4*l4+r)
    if (cw >= 63) {  // wave-uniform: no masking possible in this tile
#pragma unroll
      for (int r = 0; r < 4; ++r) {
        const int thr = 4 * l4 + r;
        const int srcl = (l4 << 4) | ((15 + l15 - thr) & 15);
        float rot[5];
#pragma unroll
        for (int p = 0; p < 5; ++p) rot[p] = __shfl(accP[p][r], srcl, 64);
        float esum = 0.f;
        const int sw2 = (thr & 7) * 8;
#pragma unroll
        for (int nt = 0; nt < 4; ++nt) {
          const float pv = (l15 <= thr) ? rot[nt] : rot[nt + 1];
          const float e = __expf(sc[nt][r] + pv);
          esum += e;
          pA[w][thr * 64 + ((16 * nt + l15) ^ sw2)] = (_Float16)e;
        }
        lsum[r] += esum;
      }
    } else {
#pragma unroll
      for (int r = 0; r < 4; ++r) {
        const int thr = 4 * l4 + r;
        const int srcl = (l4 << 4) | ((15 + l15 - thr) & 15);
        float rot[5];
#pragma unroll
        for (int p = 0; p < 5; ++p) rot[p] = __shfl(accP[p][r], srcl, 64);
        float esum = 0.f;
        const int sw2 = (thr & 7) * 8;
#pragma unroll
        for (int nt = 0; nt < 4; ++nt) {
          const float pv = (l15 <= thr) ? rot[nt] : rot[nt + 1];
          const bool masked = (16 * nt + l15) > (cw + thr);
          const float e = masked ? 0.f : __expf(sc[nt][r] + pv);
          esum += e;
          pA[w][thr * 64 + ((16 * nt + l15) ^ sw2)] = (_Float16)e;
        }
        lsum[r] += esum;
      }
    }
    // ---- PV: O += P.V ----
#pragma unroll
    for (int kk = 0; kk < 2; ++kk) {
      const half8 a8 = *(const half8*)&pA[w][l15 * 64 + ((kk * 32 + l4 * 8) ^
                                                        ((l15 & 7) * 8))];
#pragma unroll
      for (int nt = 0; nt < 4; ++nt) {
        const int row = nt * 16 + l15;
        const half8 b8 =
            *(const half8*)&vts[row * 64 + ((((kk << 2) + l4) ^ (row & 7)) * 8)];
        o[nt] = __builtin_amdgcn_mfma_f32_16x16x32_f16(a8, b8, o[nt], 0, 0, 0);
      }
    }
  }

  // ---- epilogue ----
#pragma unroll
  for (int r = 0; r < 4; ++r) {
    float s = lsum[r];
    s += __shfl_xor(s, 1, 64);
    s += __shfl_xor(s, 2, 64);
    s += __shfl_xor(s, 4, 64);
    s += __shfl_xor(s, 8, 64);
    const float inv = 1.0f / s;
    const int i = i0 + w * 16 + l4 * 4 + r;
    const size_t base = ((size_t)i * 4 + b) * 1024 + h * 64;
#pragma unroll
    for (int nt = 0; nt < 4; ++nt)
      attn_out[base + nt * 16 + l15] = (_Float16)(o[nt][r] * inv);
  }
}

// ---------------------------------------------------------------------------
extern "C" void kernel_launch(void* const* d_in, const int* in_sizes, int n_in,
                              void* d_out, int out_size, void* d_ws,
                              size_t ws_size, hipStream_t stream) {
  const float* inputs   = (const float*)d_in[0];
  const float* pos_emb  = (const float*)d_in[1];
  const float* full_inp = (const float*)d_in[2];
  const float* u        = (const float*)d_in[3];
  const float* v        = (const float*)d_in[4];
  const float* W_kv   = (const float*)d_in[6];
  const float* b_kv   = (const float*)d_in[7];
  const float* W_q    = (const float*)d_in[8];
  const float* b_q    = (const float*)d_in[9];
  const float* W_pos  = (const float*)d_in[10];
  const float* b_pos  = (const float*)d_in[11];
  const float* W_proj = (const float*)d_in[12];
  const float* b_proj = (const float*)d_in[13];
  float* out = (float*)d_out;

  char* ws = (char*)d_ws;
  const size_t MB = 1024 * 1024;
  _Float16* in_q_h    = (_Float16*)(ws);            // 8 MB  (b-major 4096x1024)
  _Float16* in_full_h = (_Float16*)(ws + 8 * MB);   // 16 MB (b-major 8192x1024)
  _Float16* in_pos_h  = (_Float16*)(ws + 24 * MB);  // 4 MB  (2048x1024)
  _Float16* attn_h    = (_Float16*)(ws + 28 * MB);  // 8 MB  (4096x1024)
  _Float16* wq_t      = (_Float16*)(ws + 36 * MB);  // 2 MB
  _Float16* wkv_t     = (_Float16*)(ws + 38 * MB);  // 4 MB
  _Float16* wpos_t    = (_Float16*)(ws + 42 * MB);  // 2 MB
  _Float16* wproj_t   = (_Float16*)(ws + 44 * MB);  // 2 MB
  _Float16* qfu       = (_Float16*)(ws + 46 * MB);  // 8 MB  [bh][1024][64]
  _Float16* kf        = (_Float16*)(ws + 54 * MB);  // 16 MB [bh][2048][64]
  _Float16* vfT       = (_Float16*)(ws + 70 * MB);  // 16 MB [bh][64][2048]
  _Float16* rf        = (_Float16*)(ws + 86 * MB);  // 4 MB  [h][2048][64]

  const dim3 blk(256);
  prep<<<dim3(15616), blk, 0, stream>>>(inputs, full_inp, pos_emb, W_q, W_kv,
                                        W_pos, W_proj, in_q_h, in_full_h,
                                        in_pos_h, wq_t, wkv_t, wpos_t, wproj_t);
  gemm3<<<dim3(1408), blk, 0, stream>>>(in_q_h, in_full_h, in_pos_h, wq_t,
                                        wkv_t, wpos_t, b_q, b_kv, b_pos, u,
                                        qfu, kf, vfT, rf);
  attn_mfma<<<dim3(1024), blk, 0, stream>>>(qfu, kf, vfT, rf, u, v, attn_h);
  gemm_proj<<<dim3(8, 32), blk, 0, stream>>>(attn_h, wproj_t, b_proj, out,
                                             4096, 1024, 1024);
}

// Round 4
// 328.043 us; speedup vs baseline: 1.1865x; 1.0375x over previous
//
#include <hip/hip_runtime.h>

// AttentionXL: CUR=1024, FULL=2048, BS=4, D=1024, HN=16, HD=64, PREV=1024
// f16 MFMA 16x16x32 everywhere; fp32 accumulate/softmax.
// Scores pre-scaled: qfu = (q+b+u)*0.125; qv = qfu + (v-u)*0.125 in-register.

typedef _Float16 half8 __attribute__((ext_vector_type(8)));
typedef _Float16 half4v __attribute__((ext_vector_type(4)));
typedef float f32x4 __attribute__((ext_vector_type(4)));

typedef const __attribute__((address_space(1))) void* gas_ptr;
typedef __attribute__((address_space(3))) void* las_ptr;

__device__ __forceinline__ void load_lds16(const void* g, void* l) {
  __builtin_amdgcn_global_load_lds((gas_ptr)g, (las_ptr)l, 16, 0, 0);
}

// ---------------------------------------------------------------------------
// prep: activation fp32->f16 with b-major row permute (blocks [0,14336)) +
// weight convert+transpose (blocks [14336,15616)).
//  in_q_h  [b*1024 + i][:] <- inputs[i*4+b][:]
//  in_full_h[b*2048 + j][:] <- full_inp[j*4+b][:]
//  in_pos_h plain copy.
// ---------------------------------------------------------------------------
__global__ __launch_bounds__(256) void prep(
    const float* __restrict__ inputs, const float* __restrict__ full_inp,
    const float* __restrict__ pos_emb, const float* __restrict__ Wq,
    const float* __restrict__ Wkv, const float* __restrict__ Wpos,
    const float* __restrict__ Wproj, _Float16* __restrict__ o_in,
    _Float16* __restrict__ o_full, _Float16* __restrict__ o_pos,
    _Float16* __restrict__ owq, _Float16* __restrict__ owkv,
    _Float16* __restrict__ owpos, _Float16* __restrict__ owproj) {
  __shared__ _Float16 tile[64][65];
  const int bx = blockIdx.x;
  const int t = threadIdx.x;
  if (bx < 14336) {
    size_t g = (size_t)bx * 256 + t;  // dst float4-group id
    const float* src;
    _Float16* dst;
    size_t sg;
    if (g < (1u << 20)) {  // inputs -> in_q_h, b-major
      const int rd = (int)(g >> 8), b = rd >> 10, i = rd & 1023;
      src = inputs; dst = o_in;
      sg = ((size_t)(i * 4 + b) << 8) + (g & 255);
    } else if (g < (3u << 20)) {  // full_inp -> in_full_h, b-major
      const size_t gd = g - (1u << 20);
      const int rd = (int)(gd >> 8), b = rd >> 11, j = rd & 2047;
      src = full_inp; dst = o_full;
      sg = ((size_t)(j * 4 + b) << 8) + (gd & 255);
      float4 vv = *(const float4*)(src + sg * 4);
      half4v hh;
      hh[0] = (_Float16)vv.x; hh[1] = (_Float16)vv.y;
      hh[2] = (_Float16)vv.z; hh[3] = (_Float16)vv.w;
      *(half4v*)(dst + gd * 4) = hh;
      return;
    } else {  // pos_emb plain
      const size_t gd = g - (3u << 20);
      float4 vv = *(const float4*)(pos_emb + gd * 4);
      half4v hh;
      hh[0] = (_Float16)vv.x; hh[1] = (_Float16)vv.y;
      hh[2] = (_Float16)vv.z; hh[3] = (_Float16)vv.w;
      *(half4v*)(o_pos + gd * 4) = hh;
      return;
    }
    // in_q_h path
    float4 vv = *(const float4*)(src + sg * 4);
    half4v hh;
    hh[0] = (_Float16)vv.x; hh[1] = (_Float16)vv.y;
    hh[2] = (_Float16)vv.z; hh[3] = (_Float16)vv.w;
    *(half4v*)(dst + (g & ((1u << 20) - 1)) * 4) = hh;
    return;
  }
  const int wb = bx - 14336;
  const float* W;
  _Float16* Wt;
  int N, tidx;
  if (wb < 256) { W = Wq; Wt = owq; N = 1024; tidx = wb; }
  else if (wb < 768) { W = Wkv; Wt = owkv; N = 2048; tidx = wb - 256; }
  else if (wb < 1024) { W = Wpos; Wt = owpos; N = 1024; tidx = wb - 768; }
  else { W = Wproj; Wt = owproj; N = 1024; tidx = wb - 1024; }
  const int K = 1024;
  const int n0 = (tidx % (N >> 6)) * 64, k0 = (tidx / (N >> 6)) * 64;
  const int rr = t >> 2, cc = (t & 3) * 16;
#pragma unroll
  for (int i = 0; i < 4; ++i) {
    float4 v = *(const float4*)&W[(size_t)(k0 + rr) * N + n0 + cc + i * 4];
    tile[rr][cc + i * 4 + 0] = (_Float16)v.x;
    tile[rr][cc + i * 4 + 1] = (_Float16)v.y;
    tile[rr][cc + i * 4 + 2] = (_Float16)v.z;
    tile[rr][cc + i * 4 + 3] = (_Float16)v.w;
  }
  __syncthreads();
  const int n = t >> 2, kc = (t & 3) * 16;
#pragma unroll
  for (int i = 0; i < 4; ++i) {
    half4v h;
    h[0] = tile[kc + i * 4 + 0][n];
    h[1] = tile[kc + i * 4 + 1][n];
    h[2] = tile[kc + i * 4 + 2][n];
    h[3] = tile[kc + i * 4 + 3][n];
    *(half4v*)&Wt[(size_t)(n0 + n) * K + k0 + kc + i * 4] = h;
  }
}

// ---------------------------------------------------------------------------
// Fused q/kv/r GEMM (A matrices are b-major). 1408 blocks.
//   [0,256):    q  -> qfu[bh][i][d] = (q+b+u)*0.125
//   [256,1280): kv -> kf[bh][j][d]; V-half via LDS transpose -> vfT[bh][d][j]
//   [1280,1408): r -> rf[h][m][d]
// ---------------------------------------------------------------------------
__global__ __launch_bounds__(256, 2) void gemm3(
    const _Float16* __restrict__ Aq, const _Float16* __restrict__ Akv,
    const _Float16* __restrict__ Ar, const _Float16* __restrict__ Btq,
    const _Float16* __restrict__ Btkv, const _Float16* __restrict__ Btr,
    const float* __restrict__ bq, const float* __restrict__ bkv,
    const float* __restrict__ br, const float* __restrict__ uu,
    _Float16* __restrict__ qfu, _Float16* __restrict__ kf,
    _Float16* __restrict__ vfT, _Float16* __restrict__ rf) {
  __shared__ _Float16 smem[128 * 66];  // K-loop: As=smem[0..4K), Bs=[4K..8K); epilogue: 128x66 tile
  _Float16* As = smem;
  _Float16* Bs = smem + 4096;
  const int gb = blockIdx.x;
  const _Float16* A;
  const _Float16* Bt;
  const float* bias;
  int mode, bm, bn;
  if (gb < 256) {
    mode = 1; A = Aq; Bt = Btq; bias = bq;
    bn = (gb & 7) * 128; bm = (gb >> 3) * 128;
  } else if (gb < 1280) {
    mode = 2; A = Akv; Bt = Btkv; bias = bkv;
    const int j = gb - 256;
    bn = (j & 15) * 128; bm = (j >> 4) * 128;
  } else {
    mode = 3; A = Ar; Bt = Btr; bias = br;
    const int j = gb - 1280;
    bn = (j & 7) * 128; bm = (j >> 3) * 128;
  }
  const int K = 1024;
  const int t = threadIdx.x, w = t >> 6, l = t & 63;
  const int l15 = l & 15, l4 = l >> 4;
  const int wm = (w >> 1) * 64, wn = (w & 1) * 64;

  f32x4 acc[4][4];
  const f32x4 z4 = {0.f, 0.f, 0.f, 0.f};
#pragma unroll
  for (int i = 0; i < 4; ++i)
#pragma unroll
    for (int j = 0; j < 4; ++j) acc[i][j] = z4;

  const char* Abase = (const char*)A + (size_t)bm * K * 2;
  const char* Bbase = (const char*)Bt + (size_t)bn * K * 2;

  for (int k0 = 0; k0 < K; k0 += 32) {
    __syncthreads();
#pragma unroll
    for (int iss = 0; iss < 2; ++iss) {
      const int off = w * 1024 + iss * 4096 + l * 16;
      const int row = off >> 6, kb = off & 63;
      load_lds16(Abase + (size_t)row * (K * 2) + k0 * 2 + kb,
                 (char*)As + off);
      load_lds16(Bbase + (size_t)row * (K * 2) + k0 * 2 + kb,
                 (char*)Bs + off);
    }
    __syncthreads();
    half8 af[4], bf[4];
#pragma unroll
    for (int mt = 0; mt < 4; ++mt)
      af[mt] = *(const half8*)&As[(wm + mt * 16 + l15) * 32 + l4 * 8];
#pragma unroll
    for (int nt = 0; nt < 4; ++nt)
      bf[nt] = *(const half8*)&Bs[(wn + nt * 16 + l15) * 32 + l4 * 8];
#pragma unroll
    for (int mt = 0; mt < 4; ++mt)
#pragma unroll
      for (int nt = 0; nt < 4; ++nt)
        acc[mt][nt] = __builtin_amdgcn_mfma_f32_16x16x32_f16(
            af[mt], bf[nt], acc[mt][nt], 0, 0, 0);
  }

  if (mode == 2 && bn >= 1024) {
    // ---- V half: LDS transpose -> coalesced vfT[bh][d][j] stores ----
    const int b = bm >> 11, j0m = bm & 2047;
    const int hbase = (bn - 1024) >> 6;  // even
#pragma unroll
    for (int ch = 0; ch < 2; ++ch) {
      __syncthreads();
      if (((wn >> 6) & 1) == ch) {
#pragma unroll
        for (int mt = 0; mt < 4; ++mt)
#pragma unroll
          for (int r = 0; r < 4; ++r) {
            const int rowl = wm + mt * 16 + l4 * 4 + r;
#pragma unroll
            for (int nt = 0; nt < 4; ++nt) {
              const int coll = nt * 16 + l15;
              smem[rowl * 66 + coll] =
                  (_Float16)(acc[mt][nt][r] + bias[bn + wn + coll]);
            }
          }
      }
      __syncthreads();
#pragma unroll
      for (int it = 0; it < 4; ++it) {
        const int c = t + 256 * it;
        const int d = c >> 4, ck = c & 15;
        half8 v8;
#pragma unroll
        for (int z = 0; z < 8; ++z) v8[z] = smem[(ck * 8 + z) * 66 + d];
        *(half8*)&vfT[(((size_t)(b * 16 + hbase + ch) * 64 + d) << 11) + j0m +
                      ck * 8] = v8;
      }
    }
    return;
  }

#pragma unroll
  for (int mt = 0; mt < 4; ++mt)
#pragma unroll
    for (int r = 0; r < 4; ++r) {
      const int rowl = wm + mt * 16 + l4 * 4 + r;
#pragma unroll
      for (int nt = 0; nt < 4; ++nt) {
        const int col = bn + wn + nt * 16 + l15;
        const float val = acc[mt][nt][r] + bias[col];
        if (mode == 1) {
          const int b = bm >> 10, i0m = bm & 1023;
          const int h = col >> 6, d = col & 63;
          qfu[(((size_t)(b * 16 + h) * 1024 + i0m + rowl) << 6) + d] =
              (_Float16)((val + uu[col]) * 0.125f);
        } else if (mode == 2) {
          const int b = bm >> 11, j0m = bm & 2047;
          const int h = col >> 6, d = col & 63;
          kf[(((size_t)(b * 16 + h) * 2048 + j0m + rowl) << 6) + d] =
              (_Float16)val;
        } else {
          const int h = col >> 6, d = col & 63;
          rf[(((size_t)h * 2048 + bm + rowl) << 6) + d] = (_Float16)val;
        }
      }
    }
}

// ---------------------------------------------------------------------------
// proj GEMM: out f32 [M][N] = A @ Bt^T + bias
// ---------------------------------------------------------------------------
__global__ __launch_bounds__(256, 2) void gemm_proj(
    const _Float16* __restrict__ A, const _Float16* __restrict__ Bt,
    const float* __restrict__ bias, float* __restrict__ out0, int M, int N,
    int K) {
  __shared__ _Float16 As[128 * 32];
  __shared__ _Float16 Bs[128 * 32];
  const int t = threadIdx.x, w = t >> 6, l = t & 63;
  const int l15 = l & 15, l4 = l >> 4;
  const int bm = blockIdx.y * 128, bn = blockIdx.x * 128;
  const int wm = (w >> 1) * 64, wn = (w & 1) * 64;

  f32x4 acc[4][4];
  const f32x4 z4 = {0.f, 0.f, 0.f, 0.f};
#pragma unroll
  for (int i = 0; i < 4; ++i)
#pragma unroll
    for (int j = 0; j < 4; ++j) acc[i][j] = z4;

  const char* Abase = (const char*)A + (size_t)bm * K * 2;
  const char* Bbase = (const char*)Bt + (size_t)bn * K * 2;

  for (int k0 = 0; k0 < K; k0 += 32) {
    __syncthreads();
#pragma unroll
    for (int iss = 0; iss < 2; ++iss) {
      const int off = w * 1024 + iss * 4096 + l * 16;
      const int row = off >> 6, kb = off & 63;
      load_lds16(Abase + (size_t)row * (K * 2) + k0 * 2 + kb,
                 (char*)As + off);
      load_lds16(Bbase + (size_t)row * (K * 2) + k0 * 2 + kb,
                 (char*)Bs + off);
    }
    __syncthreads();
    half8 af[4], bf[4];
#pragma unroll
    for (int mt = 0; mt < 4; ++mt)
      af[mt] = *(const half8*)&As[(wm + mt * 16 + l15) * 32 + l4 * 8];
#pragma unroll
    for (int nt = 0; nt < 4; ++nt)
      bf[nt] = *(const half8*)&Bs[(wn + nt * 16 + l15) * 32 + l4 * 8];
#pragma unroll
    for (int mt = 0; mt < 4; ++mt)
#pragma unroll
      for (int nt = 0; nt < 4; ++nt)
        acc[mt][nt] = __builtin_amdgcn_mfma_f32_16x16x32_f16(
            af[mt], bf[nt], acc[mt][nt], 0, 0, 0);
  }

#pragma unroll
  for (int mt = 0; mt < 4; ++mt)
#pragma unroll
    for (int r = 0; r < 4; ++r) {
      const int row = bm + wm + mt * 16 + l4 * 4 + r;
#pragma unroll
      for (int nt = 0; nt < 4; ++nt) {
        const int col = bn + wn + nt * 16 + l15;
        out0[(size_t)row * N + col] = acc[mt][nt][r] + bias[col];
      }
    }
}

// ---------------------------------------------------------------------------
// MFMA flash attention v8: 2-phase double-buffered pipeline.
//  - T3-minimum recipe: issue stage(t+1) -> compute(t) -> ONE vmcnt-drain
//    barrier per tile. The compiler's mandatory vmcnt(0) before s_barrier
//    now lands AFTER the tile's compute, hiding staging latency (round-0
//    structure exposed it: stage -> drain -> compute, 2 barriers/tile).
//  - ks/vts double-buffered (16+16 KB); rs = 256-slot ring (32 KB) staging
//    rows [m_base+128, +192) = tile t+1's new window half. Reads at t cover
//    [m_base, m_base+128): disjoint. Overwritten slots were last read at
//    tile t-2 (two barriers back): race-free with one barrier per tile.
//  - LDS 72 KB -> 2 blocks/CU (same residency as verified round-0 105.8us).
//  - math bit-identical to round-0 verified kernel.
// ---------------------------------------------------------------------------
__global__ __launch_bounds__(256, 2) void attn_mfma(
    const _Float16* __restrict__ qfu,  // [bh][1024][64]  (q+b+u)*0.125
    const _Float16* __restrict__ kf,   // [bh][2048][64]
    const _Float16* __restrict__ vfT,  // [bh][64][2048]
    const _Float16* __restrict__ rf,   // [h][2048][64]
    const float* __restrict__ u,       // [16][64]
    const float* __restrict__ v,       // [16][64]
    _Float16* __restrict__ attn_out)   // [i*4+b][1024] f16
{
  __shared__ _Float16 ks[2][64 * 64];   // [j][d] swizzled, double-buffered
  __shared__ _Float16 vts[2][64 * 64];  // [d][j] swizzled, double-buffered
  __shared__ _Float16 rs[256 * 64];     // ring (slot = m & 255), swizzled
  __shared__ _Float16 pA[4][16 * 64];   // per-wave probs, A-layout, swizzled

  const int t = threadIdx.x, w = t >> 6, l = t & 63;
  const int l15 = l & 15, l4 = l >> 4;
  const int id = blockIdx.x;
  // XCD swizzle: bh = ((id>>3)&7)*8 + (id&7); qtile = id>>6 (LPT: reversed)
  const int bh = ((id >> 3) & 7) * 8 + (id & 7);
  const int bx = 15 - (id >> 6);
  const int i0 = bx * 64;
  const int h = bh & 15, b = bh >> 4;

  const char* kfb = (const char*)(kf + (((size_t)bh * 2048) << 6));
  const char* vg = (const char*)(vfT + (((size_t)bh) << 17));
  const char* rg = (const char*)(rf + (((size_t)h) << 17));

  // q fragments; qv = qa + (v-u)*0.125 in-register
  half8 qa0, qa1, qv0, qv1;
  {
    const size_t qo = (((size_t)bh * 1024 + i0 + w * 16 + l15) << 6) + l4 * 8;
    qa0 = *(const half8*)(qfu + qo);
    qa1 = *(const half8*)(qfu + qo + 32);
    half8 dl0, dl1;
#pragma unroll
    for (int z = 0; z < 8; ++z) {
      const int di = l4 * 8 + z;
      dl0[z] = (_Float16)(0.125f * (v[h * 64 + di] - u[h * 64 + di]));
      dl1[z] = (_Float16)(0.125f * (v[h * 64 + 32 + di] - u[h * 64 + 32 + di]));
    }
    qv0 = qa0 + dl0;
    qv1 = qa1 + dl1;
  }
  const f32x4 z4 = {0.f, 0.f, 0.f, 0.f};
  f32x4 o[4];
  o[0] = z4; o[1] = z4; o[2] = z4; o[3] = z4;
  float lsum[4] = {0.f, 0.f, 0.f, 0.f};

  const int mb0 = 960 - i0;  // m_base at jt=0 (>=0, multiple of 64)
  const int njt = bx + 17;

  // ---- prologue: stage K/V tile 0 into buf0 + initial 128-row r window ----
  {
#pragma unroll
    for (int iss = 0; iss < 2; ++iss) {
      const int off = w * 1024 + iss * 4096 + l * 16;
      const int row = off >> 7;
      const int cph = (off >> 4) & 7;
      const int sw = ((cph ^ (row & 7)) << 4);
      load_lds16(kfb + (size_t)row * 128 + sw, (char*)ks[0] + off);
      load_lds16(vg + (size_t)row * 4096 + sw, (char*)vts[0] + off);
    }
  }
#pragma unroll
  for (int iss = 0; iss < 4; ++iss) {
    const int off = w * 1024 + iss * 4096 + l * 16;
    const int q = off >> 7;  // 0..127
    const int cph = (off >> 4) & 7;
    const int slot = (mb0 + q) & 255;
    int m = mb0 + q;
    m = m < 2047 ? m : 2047;
    load_lds16(rg + (size_t)m * 128 + ((cph ^ (slot & 7)) << 4),
               (char*)rs + slot * 128 + cph * 16);
  }
  __syncthreads();  // drain prologue staging

  int cur = 0;
  for (int jt = 0; jt < njt; ++jt) {
    const int j0 = jt * 64;
    const int m_base = j0 - i0 + 960;

    // ---- issue next-tile staging (flies under this tile's compute) ----
    if (jt + 1 < njt) {
      const char* kg = kfb + (size_t)(j0 + 64) * 128;
#pragma unroll
      for (int iss = 0; iss < 2; ++iss) {
        const int off = w * 1024 + iss * 4096 + l * 16;
        const int row = off >> 7;
        const int cph = (off >> 4) & 7;
        const int sw = ((cph ^ (row & 7)) << 4);
        load_lds16(kg + (size_t)row * 128 + sw, (char*)ks[cur ^ 1] + off);
        load_lds16(vg + (size_t)row * 4096 + (size_t)(j0 + 64) * 2 + sw,
                   (char*)vts[cur ^ 1] + off);
      }
      const int m0 = m_base + 128;  // tile t+1's new upper window half
#pragma unroll
      for (int iss = 0; iss < 2; ++iss) {
        const int off = w * 1024 + iss * 4096 + l * 16;
        const int q = off >> 7;  // 0..63
        const int cph = (off >> 4) & 7;
        const int slot = (m0 + q) & 255;
        int m = m0 + q;
        m = m < 2047 ? m : 2047;
        load_lds16(rg + (size_t)m * 128 + ((cph ^ (slot & 7)) << 4),
                   (char*)rs + slot * 128 + cph * 16);
      }
    }

    const _Float16* ksc = ks[cur];
    const _Float16* vtsc = vts[cur];

    // ---- content scores (16x64 per wave) ----
    f32x4 sc[4];
#pragma unroll
    for (int nt = 0; nt < 4; ++nt) {
      const int row = nt * 16 + l15;
      const int rsw = row & 7;
      const half8 b0 = *(const half8*)&ksc[row * 64 + ((l4 ^ rsw) * 8)];
      const half8 b1 = *(const half8*)&ksc[row * 64 + (((4 + l4) ^ rsw) * 8)];
      f32x4 cc = z4;
      cc = __builtin_amdgcn_mfma_f32_16x16x32_f16(qa0, b0, cc, 0, 0, 0);
      cc = __builtin_amdgcn_mfma_f32_16x16x32_f16(qa1, b1, cc, 0, 0, 0);
      sc[nt] = cc;
    }
    // ---- position scores: 5 tiles over this wave's 79-wide window ----
    f32x4 accP[5];
#pragma unroll
    for (int p = 0; p < 5; ++p) {
      const int m = m_base + (3 - w + p) * 16 + l15;
      const int slot = m & 255;
      const int ssw = slot & 7;
      const half8 b0 = *(const half8*)&rs[slot * 64 + ((l4 ^ ssw) * 8)];
      const half8 b1 = *(const half8*)&rs[slot * 64 + (((4 + l4) ^ ssw) * 8)];
      f32x4 cc = z4;
      cc = __builtin_amdgcn_mfma_f32_16x16x32_f16(qv0, b0, cc, 0, 0, 0);
      cc = __builtin_amdgcn_mfma_f32_16x16x32_f16(qv1, b1, cc, 0, 0, 0);
      accP[p] = cc;
    }

    // ---- softmax + P into A-layout (scores pre-scaled by 0.125) ----
    const int cw = i0 - j0 + 1024 + 16 * w;  // mask: jl > cw + (4*l4+r)
    if (cw >= 63) {  // wave-uniform: no masking possible in this tile
#pragma unroll
      for (int r = 0; r < 4; ++r) {
        const int thr = 4 * l4 + r;
        const int srcl = (l4 << 4) | ((15 + l15 - thr) & 15);
        float rot[5];
#pragma unroll
        for (int p = 0; p < 5; ++p) rot[p] = __shfl(accP[p][r], srcl, 64);
        float esum = 0.f;
        const int sw2 = (thr & 7) * 8;
#pragma unroll
        for (int nt = 0; nt < 4; ++nt) {
          const float pv = (l15 <= thr) ? rot[nt] : rot[nt + 1];
          const float e = __expf(sc[nt][r] + pv);
          esum += e;
          pA[w][thr * 64 + ((16 * nt + l15) ^ sw2)] = (_Float16)e;
        }
        lsum[r] += esum;
      }
    } else {
#pragma unroll
      for (int r = 0; r < 4; ++r) {
        const int thr = 4 * l4 + r;
        const int srcl = (l4 << 4) | ((15 + l15 - thr) & 15);
        float rot[5];
#pragma unroll
        for (int p = 0; p < 5; ++p) rot[p] = __shfl(accP[p][r], srcl, 64);
        float esum = 0.f;
        const int sw2 = (thr & 7) * 8;
#pragma unroll
        for (int nt = 0; nt < 4; ++nt) {
          const float pv = (l15 <= thr) ? rot[nt] : rot[nt + 1];
          const bool masked = (16 * nt + l15) > (cw + thr);
          const float e = masked ? 0.f : __expf(sc[nt][r] + pv);
          esum += e;
          pA[w][thr * 64 + ((16 * nt + l15) ^ sw2)] = (_Float16)e;
        }
        lsum[r] += esum;
      }
    }
    // ---- PV: O += P.V ----
#pragma unroll
    for (int kk = 0; kk < 2; ++kk) {
      const half8 a8 = *(const half8*)&pA[w][l15 * 64 + ((kk * 32 + l4 * 8) ^
                                                        ((l15 & 7) * 8))];
#pragma unroll
      for (int nt = 0; nt < 4; ++nt) {
        const int row = nt * 16 + l15;
        const half8 b8 = *(const half8*)&vtsc[row * 64 +
                                             ((((kk << 2) + l4) ^ (row & 7)) * 8)];
        o[nt] = __builtin_amdgcn_mfma_f32_16x16x32_f16(a8, b8, o[nt], 0, 0, 0);
      }
    }

    __syncthreads();  // single per-tile drain: stage(t+1) lands AFTER compute
    cur ^= 1;
  }

  // ---- epilogue ----
#pragma unroll
  for (int r = 0; r < 4; ++r) {
    float s = lsum[r];
    s += __shfl_xor(s, 1, 64);
    s += __shfl_xor(s, 2, 64);
    s += __shfl_xor(s, 4, 64);
    s += __shfl_xor(s, 8, 64);
    const float inv = 1.0f / s;
    const int i = i0 + w * 16 + l4 * 4 + r;
    const size_t base = ((size_t)i * 4 + b) * 1024 + h * 64;
#pragma unroll
    for (int nt = 0; nt < 4; ++nt)
      attn_out[base + nt * 16 + l15] = (_Float16)(o[nt][r] * inv);
  }
}

// ---------------------------------------------------------------------------
extern "C" void kernel_launch(void* const* d_in, const int* in_sizes, int n_in,
                              void* d_out, int out_size, void* d_ws,
                              size_t ws_size, hipStream_t stream) {
  const float* inputs   = (const float*)d_in[0];
  const float* pos_emb  = (const float*)d_in[1];
  const float* full_inp = (const float*)d_in[2];
  const float* u        = (const float*)d_in[3];
  const float* v        = (const float*)d_in[4];
  const float* W_kv   = (const float*)d_in[6];
  const float* b_kv   = (const float*)d_in[7];
  const float* W_q    = (const float*)d_in[8];
  const float* b_q    = (const float*)d_in[9];
  const float* W_pos  = (const float*)d_in[10];
  const float* b_pos  = (const float*)d_in[11];
  const float* W_proj = (const float*)d_in[12];
  const float* b_proj = (const float*)d_in[13];
  float* out = (float*)d_out;

  char* ws = (char*)d_ws;
  const size_t MB = 1024 * 1024;
  _Float16* in_q_h    = (_Float16*)(ws);            // 8 MB  (b-major 4096x1024)
  _Float16* in_full_h = (_Float16*)(ws + 8 * MB);   // 16 MB (b-major 8192x1024)
  _Float16* in_pos_h  = (_Float16*)(ws + 24 * MB);  // 4 MB  (2048x1024)
  _Float16* attn_h    = (_Float16*)(ws + 28 * MB);  // 8 MB  (4096x1024)
  _Float16* wq_t      = (_Float16*)(ws + 36 * MB);  // 2 MB
  _Float16* wkv_t     = (_Float16*)(ws + 38 * MB);  // 4 MB
  _Float16* wpos_t    = (_Float16*)(ws + 42 * MB);  // 2 MB
  _Float16* wproj_t   = (_Float16*)(ws + 44 * MB);  // 2 MB
  _Float16* qfu       = (_Float16*)(ws + 46 * MB);  // 8 MB  [bh][1024][64]
  _Float16* kf        = (_Float16*)(ws + 54 * MB);  // 16 MB [bh][2048][64]
  _Float16* vfT       = (_Float16*)(ws + 70 * MB);  // 16 MB [bh][64][2048]
  _Float16* rf        = (_Float16*)(ws + 86 * MB);  // 4 MB  [h][2048][64]

  const dim3 blk(256);
  prep<<<dim3(15616), blk, 0, stream>>>(inputs, full_inp, pos_emb, W_q, W_kv,
                                        W_pos, W_proj, in_q_h, in_full_h,
                                        in_pos_h, wq_t, wkv_t, wpos_t, wproj_t);
  gemm3<<<dim3(1408), blk, 0, stream>>>(in_q_h, in_full_h, in_pos_h, wq_t,
                                        wkv_t, wpos_t, b_q, b_kv, b_pos, u,
                                        qfu, kf, vfT, rf);
  attn_mfma<<<dim3(1024), blk, 0, stream>>>(qfu, kf, vfT, rf, u, v, attn_h);
  gemm_proj<<<dim3(8, 32), blk, 0, stream>>>(attn_h, wproj_t, b_proj, out,
                                             4096, 1024, 1024);
}